// Round 5
// baseline (197.794 us; speedup 1.0000x reference)
//
#include <hip/hip_runtime.h>

#define L_SEQ 4096
#define DIN   512
#define NST   256

// ---------------------------------------------------------------------------
// prep: A_bar (complex, per n) and Bm = [re(B_bar); im(B_bar)] as [512][512]
// ---------------------------------------------------------------------------
__global__ __launch_bounds__(256) void prep_kernel(
    const float* __restrict__ A_real, const float* __restrict__ A_imag,
    const float* __restrict__ B_mat, float* __restrict__ abr,
    float* __restrict__ abi, float* __restrict__ bm) {
  const int n = blockIdx.x;
  const float ar = -fabsf(A_real[n]) - 5e-4f;
  const float ai = A_imag[n];
  const float dr = 1.0f - 0.005f * ar;     // denom = dr + i*di
  const float di = -0.005f * ai;
  const float inv = 1.0f / (dr * dr + di * di);
  if (threadIdx.x == 0) {
    const float nr = 1.0f + 0.005f * ar;
    const float ni = 0.005f * ai;
    abr[n] = (nr * dr + ni * di) * inv;
    abi[n] = (ni * dr - nr * di) * inv;
  }
  const float cr = 0.01f * dr * inv;       // B_bar = B * (cr + i*ci)
  const float ci = -0.01f * di * inv;
  for (int d = threadIdx.x; d < DIN; d += blockDim.x) {
    const float bv = B_mat[n * DIN + d];
    bm[n * DIN + d]         = bv * cr;     // re rows 0..255
    bm[(NST + n) * DIN + d] = bv * ci;     // im rows 256..511
  }
}

// ---------------------------------------------------------------------------
// GEMM1: V[b][j][l] = sum_d U[b,l,d] * Bm[j,d]   (j = reim*256 + n)
// 64x64 tile, BK=16, 4x4 per thread (consecutive), transposed store.
// ---------------------------------------------------------------------------
__global__ __launch_bounds__(256) void gemm1_kernel(
    const float* __restrict__ U, const float* __restrict__ Bm,
    float* __restrict__ V) {
  __shared__ float As[16][68];   // [k][m]
  __shared__ float Bs[16][68];   // [k][j]
  const int tid = threadIdx.x;
  const int m0 = blockIdx.x * 64;
  const int j0 = blockIdx.y * 64;
  const int lr = tid >> 2;             // load row 0..63
  const int lc = (tid & 3) << 2;       // load col 0,4,8,12
  const int tc = tid & 15;             // m group (4 consecutive)
  const int tr = tid >> 4;             // j group (4 consecutive)
  float acc[4][4] = {};                // acc[j][i]
  for (int k0 = 0; k0 < DIN; k0 += 16) {
    const float4 av = *reinterpret_cast<const float4*>(&U[(size_t)(m0 + lr) * DIN + k0 + lc]);
    const float4 bv = *reinterpret_cast<const float4*>(&Bm[(size_t)(j0 + lr) * DIN + k0 + lc]);
    __syncthreads();
    As[lc + 0][lr] = av.x; As[lc + 1][lr] = av.y; As[lc + 2][lr] = av.z; As[lc + 3][lr] = av.w;
    Bs[lc + 0][lr] = bv.x; Bs[lc + 1][lr] = bv.y; Bs[lc + 2][lr] = bv.z; Bs[lc + 3][lr] = bv.w;
    __syncthreads();
#pragma unroll
    for (int k = 0; k < 16; ++k) {
      const float4 a  = *reinterpret_cast<const float4*>(&As[k][tc * 4]);
      const float4 bq = *reinterpret_cast<const float4*>(&Bs[k][tr * 4]);
      const float aa[4] = {a.x, a.y, a.z, a.w};
      const float bb[4] = {bq.x, bq.y, bq.z, bq.w};
#pragma unroll
      for (int j = 0; j < 4; ++j)
#pragma unroll
        for (int i = 0; i < 4; ++i) acc[j][i] += aa[i] * bb[j];
    }
  }
  const int b  = m0 >> 12;
  const int l0 = (m0 & 4095) + tc * 4;
#pragma unroll
  for (int j = 0; j < 4; ++j) {
    const float4 o = make_float4(acc[j][0], acc[j][1], acc[j][2], acc[j][3]);
    *reinterpret_cast<float4*>(&V[((size_t)b * 512 + (j0 + tr * 4 + j)) * L_SEQ + l0]) = o;
  }
}

// ---------------------------------------------------------------------------
// scan: per (b,n), y[l] = A_bar*y[l-1] + v[l]; write Re(y) as Y[b][n][l]
// 256 threads x 16 local elems + Hillis-Steele block scan (factor a^16)
// ---------------------------------------------------------------------------
__global__ __launch_bounds__(256) void scan_kernel(
    const float* __restrict__ V, const float* __restrict__ abr,
    const float* __restrict__ abi, float* __restrict__ Y) {
  const int b = blockIdx.x >> 8;
  const int n = blockIdx.x & 255;
  const float ar = abr[n], ai = abi[n];
  const float* vre = V + ((size_t)b * 512 + n) * L_SEQ;
  const float* vim = V + ((size_t)b * 512 + NST + n) * L_SEQ;
  const int t = threadIdx.x;

  float xr[16], xi[16];
#pragma unroll
  for (int q = 0; q < 4; ++q) {
    const float4 a4 = *reinterpret_cast<const float4*>(&vre[t * 16 + q * 4]);
    const float4 b4 = *reinterpret_cast<const float4*>(&vim[t * 16 + q * 4]);
    xr[q * 4 + 0] = a4.x; xr[q * 4 + 1] = a4.y; xr[q * 4 + 2] = a4.z; xr[q * 4 + 3] = a4.w;
    xi[q * 4 + 0] = b4.x; xi[q * 4 + 1] = b4.y; xi[q * 4 + 2] = b4.z; xi[q * 4 + 3] = b4.w;
  }
  // local sequential scan
  float yr = 0.f, yi = 0.f;
#pragma unroll
  for (int i = 0; i < 16; ++i) {
    const float t1 = ar * yr - ai * yi + xr[i];
    yi = ar * yi + ai * yr + xi[i];
    yr = t1;
    xr[i] = yr; xi[i] = yi;
  }
  // f = a^16
  float fr = ar, fi = ai;
#pragma unroll
  for (int s = 0; s < 4; ++s) { const float t2 = fr * fr - fi * fi; fi = 2.f * fr * fi; fr = t2; }
  // inclusive Hillis-Steele scan of segment end values
  __shared__ float sr[256], si[256];
  float er = yr, ei = yi;
  for (int s = 1; s < 256; s <<= 1) {
    sr[t] = er; si[t] = ei;
    __syncthreads();
    if (t >= s) {
      const float pr = sr[t - s], pi = si[t - s];
      er += fr * pr - fi * pi;
      ei += fr * pi + fi * pr;
    }
    __syncthreads();
    const float t2 = fr * fr - fi * fi; fi = 2.f * fr * fi; fr = t2;
  }
  // exclusive carry = inclusive value of thread t-1
  sr[t] = er; si[t] = ei;
  __syncthreads();
  float cr = 0.f, ci = 0.f;
  if (t > 0) { cr = sr[t - 1]; ci = si[t - 1]; }
  // fixup: y_global_i = y_local_i + a^(i+1) * carry ; keep only real part
  float ov[16];
  float gr = cr, gi = ci;
#pragma unroll
  for (int i = 0; i < 16; ++i) {
    const float t1 = ar * gr - ai * gi;
    gi = ar * gi + ai * gr;
    gr = t1;
    ov[i] = xr[i] + gr;
  }
  float* yo = Y + ((size_t)b * NST + n) * L_SEQ + t * 16;
#pragma unroll
  for (int q = 0; q < 4; ++q)
    *reinterpret_cast<float4*>(&yo[q * 4]) =
        make_float4(ov[q * 4 + 0], ov[q * 4 + 1], ov[q * 4 + 2], ov[q * 4 + 3]);
}

// ---------------------------------------------------------------------------
// GEMM2: out[b,l,d] = sum_n Y[b][n][l] * Cm[d,n] + U[b,l,d]*Dv[d]
// ---------------------------------------------------------------------------
__global__ __launch_bounds__(256) void gemm2_kernel(
    const float* __restrict__ Y, const float* __restrict__ Cm,
    const float* __restrict__ U, const float* __restrict__ Dv,
    float* __restrict__ out) {
  __shared__ float As[16][68];   // [n][l]
  __shared__ float Bs[16][68];   // [n][d]
  const int tid = threadIdx.x;
  const int m0 = blockIdx.x * 64;
  const int d0 = blockIdx.y * 64;
  const int b   = m0 >> 12;
  const int l00 = m0 & 4095;
  const int ar_ = tid >> 4;            // n row 0..15 (A load)
  const int ac  = (tid & 15) << 2;     // l col
  const int br_ = tid >> 2;            // d row 0..63 (B load)
  const int bc  = (tid & 3) << 2;      // n col
  const int tc = tid & 15;             // d group
  const int tr = tid >> 4;             // l group
  float acc[4][4] = {};                // acc[i(l)][j(d)]
  for (int k0 = 0; k0 < NST; k0 += 16) {
    const float4 av = *reinterpret_cast<const float4*>(
        &Y[((size_t)b * NST + k0 + ar_) * L_SEQ + l00 + ac]);
    const float4 bv = *reinterpret_cast<const float4*>(
        &Cm[(size_t)(d0 + br_) * NST + k0 + bc]);
    __syncthreads();
    *reinterpret_cast<float4*>(&As[ar_][ac]) = av;
    Bs[bc + 0][br_] = bv.x; Bs[bc + 1][br_] = bv.y; Bs[bc + 2][br_] = bv.z; Bs[bc + 3][br_] = bv.w;
    __syncthreads();
#pragma unroll
    for (int k = 0; k < 16; ++k) {
      const float4 a  = *reinterpret_cast<const float4*>(&As[k][tr * 4]);
      const float4 bq = *reinterpret_cast<const float4*>(&Bs[k][tc * 4]);
      const float aa[4] = {a.x, a.y, a.z, a.w};
      const float bb[4] = {bq.x, bq.y, bq.z, bq.w};
#pragma unroll
      for (int i = 0; i < 4; ++i)
#pragma unroll
        for (int j = 0; j < 4; ++j) acc[i][j] += aa[i] * bb[j];
    }
  }
#pragma unroll
  for (int i = 0; i < 4; ++i) {
    const int l = l00 + tr * 4 + i;
    const size_t base = ((size_t)b * L_SEQ + l) * DIN + d0 + tc * 4;
    const float4 uv = *reinterpret_cast<const float4*>(&U[base]);
    const float4 dv = *reinterpret_cast<const float4*>(&Dv[d0 + tc * 4]);
    float4 o;
    o.x = acc[i][0] + uv.x * dv.x;
    o.y = acc[i][1] + uv.y * dv.y;
    o.z = acc[i][2] + uv.z * dv.z;
    o.w = acc[i][3] + uv.w * dv.w;
    *reinterpret_cast<float4*>(&out[base]) = o;
  }
}

// ---------------------------------------------------------------------------
extern "C" void kernel_launch(void* const* d_in, const int* in_sizes, int n_in,
                              void* d_out, int out_size, void* d_ws, size_t ws_size,
                              hipStream_t stream) {
  const float* u      = (const float*)d_in[0];
  const float* A_real = (const float*)d_in[1];
  const float* A_imag = (const float*)d_in[2];
  const float* B_mat  = (const float*)d_in[3];
  const float* C_mat  = (const float*)d_in[4];
  const float* D_vec  = (const float*)d_in[5];
  float* out = (float*)d_out;

  float* ws  = (float*)d_ws;
  float* bm  = ws;                             // 512*512
  float* abr = bm + 512 * 512;                 // 256
  float* abi = abr + 256;                      // 256
  float* V   = abi + 256;                      // 4*512*4096
  float* Y   = V + (size_t)4 * 512 * 4096;     // 4*256*4096

  hipLaunchKernelGGL(prep_kernel, dim3(NST), dim3(256), 0, stream,
                     A_real, A_imag, B_mat, abr, abi, bm);
  hipLaunchKernelGGL(gemm1_kernel, dim3(256, 8), dim3(256), 0, stream, u, bm, V);
  hipLaunchKernelGGL(scan_kernel, dim3(1024), dim3(256), 0, stream, V, abr, abi, Y);
  hipLaunchKernelGGL(gemm2_kernel, dim3(256, 8), dim3(256), 0, stream, Y, C_mat, u, D_vec, out);
}

// Round 6
// 105.833 us; speedup vs baseline: 1.8689x; 1.8689x over previous
//
#include <hip/hip_runtime.h>

#define L_SEQ 4096
#define DIN   512
#define NST   256

typedef __attribute__((ext_vector_type(8))) short short8;
typedef __attribute__((ext_vector_type(4))) float f32x4;

__device__ inline unsigned short f2bf(float f) {
  unsigned u = __builtin_bit_cast(unsigned, f);
  unsigned r = (u + 0x7FFFu + ((u >> 16) & 1u)) >> 16;   // RTN-even
  return (unsigned short)r;
}
__device__ inline float bf2f(unsigned short h) {
  unsigned u = ((unsigned)h) << 16;
  return __builtin_bit_cast(float, u);
}

// ---------------------------------------------------------------------------
// prep: A_bar (complex per n); Bmbf = [re(B_bar); im(B_bar)] as bf16 [512][512]
// ---------------------------------------------------------------------------
__global__ __launch_bounds__(256) void prep_kernel(
    const float* __restrict__ A_real, const float* __restrict__ A_imag,
    const float* __restrict__ B_mat, float* __restrict__ abr,
    float* __restrict__ abi, unsigned short* __restrict__ bmbf) {
  const int n = blockIdx.x;
  const float ar = -fabsf(A_real[n]) - 5e-4f;
  const float ai = A_imag[n];
  const float dr = 1.0f - 0.005f * ar;
  const float di = -0.005f * ai;
  const float inv = 1.0f / (dr * dr + di * di);
  if (threadIdx.x == 0) {
    const float nr = 1.0f + 0.005f * ar;
    const float ni = 0.005f * ai;
    abr[n] = (nr * dr + ni * di) * inv;
    abi[n] = (ni * dr - nr * di) * inv;
  }
  const float cr = 0.01f * dr * inv;
  const float ci = -0.01f * di * inv;
  for (int d = threadIdx.x; d < DIN; d += blockDim.x) {
    const float bv = B_mat[n * DIN + d];
    bmbf[n * DIN + d]         = f2bf(bv * cr);
    bmbf[(NST + n) * DIN + d] = f2bf(bv * ci);
  }
}

// ---------------------------------------------------------------------------
// cvt: U fp32 -> Ubf bf16 (8 elems/thread)
// ---------------------------------------------------------------------------
__global__ __launch_bounds__(256) void cvt_kernel(
    const float* __restrict__ U, unsigned short* __restrict__ Ubf) {
  const int i = blockIdx.x * 256 + threadIdx.x;   // chunk of 8
  const float4 f0 = reinterpret_cast<const float4*>(U)[i * 2];
  const float4 f1 = reinterpret_cast<const float4*>(U)[i * 2 + 1];
  unsigned short o[8] = {f2bf(f0.x), f2bf(f0.y), f2bf(f0.z), f2bf(f0.w),
                         f2bf(f1.x), f2bf(f1.y), f2bf(f1.z), f2bf(f1.w)};
  *reinterpret_cast<short8*>(&Ubf[(size_t)i * 8]) = *reinterpret_cast<short8*>(o);
}

// ---------------------------------------------------------------------------
// GEMM1 (MFMA): V[b][j][l] (bf16) = sum_d Ubf[m=(b,l)][d] * Bmbf[j][d]
// 128x128 tile, BK=32, 4 waves (2x2), 4x4 fragments/wave, global_load_lds dbuf
// ---------------------------------------------------------------------------
__global__ __launch_bounds__(256, 2) void gemm1_mfma(
    const unsigned short* __restrict__ Ubf,
    const unsigned short* __restrict__ Bmbf,
    unsigned short* __restrict__ V) {
  __shared__ short At[2][128 * 32];   // [row][k] 64B rows, 8KB per buf
  __shared__ short Bt[2][128 * 32];
  const int tid  = threadIdx.x;
  const int wave = tid >> 6;
  const int lane = tid & 63;
  const int m0 = blockIdx.x * 128;
  const int j0 = blockIdx.y * 128;

  f32x4 acc[4][4];
#pragma unroll
  for (int i = 0; i < 4; ++i)
#pragma unroll
    for (int j = 0; j < 4; ++j) acc[i][j] = (f32x4)0.f;

  const int wr = wave >> 1, wc = wave & 1;   // wave -> 64x64 quadrant
  const int cl = lane & 15;
  const int kq = lane >> 4;

#define STAGE(buf, k0)                                                          \
  {                                                                             \
    _Pragma("unroll")                                                           \
    for (int q = 0; q < 2; ++q) {                                               \
      const int row = wave * 32 + q * 16 + (lane >> 2);                         \
      const int kb  = lane & 3;                                                 \
      const unsigned short* gA = Ubf  + (size_t)(m0 + row) * 512 + (k0) + kb*8; \
      const unsigned short* gB = Bmbf + (size_t)(j0 + row) * 512 + (k0) + kb*8; \
      short* lA = &At[buf][(wave * 32 + q * 16) * 32];                          \
      short* lB = &Bt[buf][(wave * 32 + q * 16) * 32];                          \
      __builtin_amdgcn_global_load_lds(                                         \
          (const __attribute__((address_space(1))) void*)gA,                    \
          (__attribute__((address_space(3))) void*)lA, 16, 0, 0);               \
      __builtin_amdgcn_global_load_lds(                                         \
          (const __attribute__((address_space(1))) void*)gB,                    \
          (__attribute__((address_space(3))) void*)lB, 16, 0, 0);               \
    }                                                                           \
  }

  STAGE(0, 0)
  for (int s = 0; s < 16; ++s) {
    const int cur = s & 1;
    if (s < 15) STAGE(cur ^ 1, (s + 1) * 32)
    __syncthreads();                 // compiler drains vmcnt before barrier
    short8 a[4], b[4];
#pragma unroll
    for (int f = 0; f < 4; ++f) {
      a[f] = *reinterpret_cast<const short8*>(&At[cur][(wr * 64 + f * 16 + cl) * 32 + kq * 8]);
      b[f] = *reinterpret_cast<const short8*>(&Bt[cur][(wc * 64 + f * 16 + cl) * 32 + kq * 8]);
    }
#pragma unroll
    for (int fm = 0; fm < 4; ++fm)
#pragma unroll
      for (int fn = 0; fn < 4; ++fn)
        acc[fm][fn] = __builtin_amdgcn_mfma_f32_16x16x32_bf16(a[fm], b[fn], acc[fm][fn], 0, 0, 0);
    __syncthreads();
  }
#undef STAGE

  // C/D layout: col(j)=lane&15, row(l)=(lane>>4)*4+reg  -> 4 consecutive l
  const int bb    = m0 >> 12;
  const int lbase = (m0 & 4095);
#pragma unroll
  for (int fm = 0; fm < 4; ++fm)
#pragma unroll
    for (int fn = 0; fn < 4; ++fn) {
      const int jj = j0 + wc * 64 + fn * 16 + cl;
      const int ll = lbase + wr * 64 + fm * 16 + kq * 4;
      const f32x4 v = acc[fm][fn];
      unsigned short o[4] = {f2bf(v.x), f2bf(v.y), f2bf(v.z), f2bf(v.w)};
      *reinterpret_cast<ushort4*>(&V[((size_t)bb * 512 + jj) * L_SEQ + ll]) =
          *reinterpret_cast<ushort4*>(o);
    }
}

// ---------------------------------------------------------------------------
// scan: per (b,n), y[l] = A_bar*y[l-1] + v[l]; V bf16 in, Re(y) fp32 out
// ---------------------------------------------------------------------------
__global__ __launch_bounds__(256) void scan_kernel(
    const unsigned short* __restrict__ V, const float* __restrict__ abr,
    const float* __restrict__ abi, float* __restrict__ Y) {
  const int b = blockIdx.x >> 8;
  const int n = blockIdx.x & 255;
  const float ar = abr[n], ai = abi[n];
  const unsigned short* vre = V + ((size_t)b * 512 + n) * L_SEQ;
  const unsigned short* vim = V + ((size_t)b * 512 + NST + n) * L_SEQ;
  const int t = threadIdx.x;

  float xr[16], xi[16];
#pragma unroll
  for (int q = 0; q < 2; ++q) {
    const short8 r8 = *reinterpret_cast<const short8*>(&vre[t * 16 + q * 8]);
    const short8 i8 = *reinterpret_cast<const short8*>(&vim[t * 16 + q * 8]);
#pragma unroll
    for (int j = 0; j < 8; ++j) {
      xr[q * 8 + j] = bf2f((unsigned short)r8[j]);
      xi[q * 8 + j] = bf2f((unsigned short)i8[j]);
    }
  }
  float yr = 0.f, yi = 0.f;
#pragma unroll
  for (int i = 0; i < 16; ++i) {
    const float t1 = ar * yr - ai * yi + xr[i];
    yi = ar * yi + ai * yr + xi[i];
    yr = t1;
    xr[i] = yr; xi[i] = yi;
  }
  float fr = ar, fi = ai;
#pragma unroll
  for (int s = 0; s < 4; ++s) { const float t2 = fr * fr - fi * fi; fi = 2.f * fr * fi; fr = t2; }
  __shared__ float sr[256], si[256];
  float er = yr, ei = yi;
  for (int s = 1; s < 256; s <<= 1) {
    sr[t] = er; si[t] = ei;
    __syncthreads();
    if (t >= s) {
      const float pr = sr[t - s], pi = si[t - s];
      er += fr * pr - fi * pi;
      ei += fr * pi + fi * pr;
    }
    __syncthreads();
    const float t2 = fr * fr - fi * fi; fi = 2.f * fr * fi; fr = t2;
  }
  sr[t] = er; si[t] = ei;
  __syncthreads();
  float cr = 0.f, ci = 0.f;
  if (t > 0) { cr = sr[t - 1]; ci = si[t - 1]; }
  float ov[16];
  float gr = cr, gi = ci;
#pragma unroll
  for (int i = 0; i < 16; ++i) {
    const float t1 = ar * gr - ai * gi;
    gi = ar * gi + ai * gr;
    gr = t1;
    ov[i] = xr[i] + gr;
  }
  float* yo = Y + ((size_t)b * NST + n) * L_SEQ + t * 16;
#pragma unroll
  for (int q = 0; q < 4; ++q)
    *reinterpret_cast<float4*>(&yo[q * 4]) =
        make_float4(ov[q * 4 + 0], ov[q * 4 + 1], ov[q * 4 + 2], ov[q * 4 + 3]);
}

// ---------------------------------------------------------------------------
// GEMM2 (fp32): out[b,l,d] = sum_n Y[b][n][l] * Cm[d,n] + U[b,l,d]*Dv[d]
// ---------------------------------------------------------------------------
__global__ __launch_bounds__(256) void gemm2_kernel(
    const float* __restrict__ Y, const float* __restrict__ Cm,
    const float* __restrict__ U, const float* __restrict__ Dv,
    float* __restrict__ out) {
  __shared__ float As[16][68];
  __shared__ float Bs[16][68];
  const int tid = threadIdx.x;
  const int m0 = blockIdx.x * 64;
  const int d0 = blockIdx.y * 64;
  const int b   = m0 >> 12;
  const int l00 = m0 & 4095;
  const int ar_ = tid >> 4;
  const int ac  = (tid & 15) << 2;
  const int br_ = tid >> 2;
  const int bc  = (tid & 3) << 2;
  const int tc = tid & 15;
  const int tr = tid >> 4;
  float acc[4][4] = {};
  for (int k0 = 0; k0 < NST; k0 += 16) {
    const float4 av = *reinterpret_cast<const float4*>(
        &Y[((size_t)b * NST + k0 + ar_) * L_SEQ + l00 + ac]);
    const float4 bv = *reinterpret_cast<const float4*>(
        &Cm[(size_t)(d0 + br_) * NST + k0 + bc]);
    __syncthreads();
    *reinterpret_cast<float4*>(&As[ar_][ac]) = av;
    Bs[bc + 0][br_] = bv.x; Bs[bc + 1][br_] = bv.y; Bs[bc + 2][br_] = bv.z; Bs[bc + 3][br_] = bv.w;
    __syncthreads();
#pragma unroll
    for (int k = 0; k < 16; ++k) {
      const float4 a  = *reinterpret_cast<const float4*>(&As[k][tr * 4]);
      const float4 bq = *reinterpret_cast<const float4*>(&Bs[k][tc * 4]);
      const float aa[4] = {a.x, a.y, a.z, a.w};
      const float bb[4] = {bq.x, bq.y, bq.z, bq.w};
#pragma unroll
      for (int i = 0; i < 4; ++i)
#pragma unroll
        for (int j = 0; j < 4; ++j) acc[i][j] += aa[i] * bb[j];
    }
  }
#pragma unroll
  for (int i = 0; i < 4; ++i) {
    const int l = l00 + tr * 4 + i;
    const size_t base = ((size_t)b * L_SEQ + l) * DIN + d0 + tc * 4;
    const float4 uv = *reinterpret_cast<const float4*>(&U[base]);
    const float4 dv = *reinterpret_cast<const float4*>(&Dv[d0 + tc * 4]);
    float4 o;
    o.x = acc[i][0] + uv.x * dv.x;
    o.y = acc[i][1] + uv.y * dv.y;
    o.z = acc[i][2] + uv.z * dv.z;
    o.w = acc[i][3] + uv.w * dv.w;
    *reinterpret_cast<float4*>(&out[base]) = o;
  }
}

// ---------------------------------------------------------------------------
extern "C" void kernel_launch(void* const* d_in, const int* in_sizes, int n_in,
                              void* d_out, int out_size, void* d_ws, size_t ws_size,
                              hipStream_t stream) {
  const float* u      = (const float*)d_in[0];
  const float* A_real = (const float*)d_in[1];
  const float* A_imag = (const float*)d_in[2];
  const float* B_mat  = (const float*)d_in[3];
  const float* C_mat  = (const float*)d_in[4];
  const float* D_vec  = (const float*)d_in[5];
  float* out = (float*)d_out;

  unsigned short* bmbf = (unsigned short*)d_ws;            // 512*512 bf16
  float* abr = (float*)(bmbf + 512 * 512);                 // 256
  float* abi = abr + 256;                                  // 256
  unsigned short* Ubf = (unsigned short*)(abi + 256);      // 16384*512 bf16
  unsigned short* V   = Ubf + (size_t)16384 * 512;         // 4*512*4096 bf16
  float* Y = (float*)(V + (size_t)4 * 512 * 4096);         // 4*256*4096 f32

  hipLaunchKernelGGL(prep_kernel, dim3(NST), dim3(256), 0, stream,
                     A_real, A_imag, B_mat, abr, abi, bmbf);
  hipLaunchKernelGGL(cvt_kernel, dim3(4096), dim3(256), 0, stream, u, Ubf);
  hipLaunchKernelGGL(gemm1_mfma, dim3(128, 4), dim3(256), 0, stream, Ubf, bmbf, V);
  hipLaunchKernelGGL(scan_kernel, dim3(1024), dim3(256), 0, stream, V, abr, abi, Y);
  hipLaunchKernelGGL(gemm2_kernel, dim3(256, 8), dim3(256), 0, stream, Y, C_mat, u, D_vec, out);
}

// Round 7
// 66.617 us; speedup vs baseline: 2.9691x; 1.5887x over previous
//
#include <hip/hip_runtime.h>

#define L_SEQ 4096
#define DIN   512
#define NST   256

typedef __attribute__((ext_vector_type(8))) short short8;
typedef __attribute__((ext_vector_type(4))) float f32x4;

__device__ inline unsigned short f2bf(float f) {
  unsigned u = __builtin_bit_cast(unsigned, f);
  unsigned r = (u + 0x7FFFu + ((u >> 16) & 1u)) >> 16;   // RTN-even
  return (unsigned short)r;
}
__device__ inline float bf2f(unsigned short h) {
  unsigned u = ((unsigned)h) << 16;
  return __builtin_bit_cast(float, u);
}

// ---------------------------------------------------------------------------
// prep: A_bar; Bmbf = [re(B_bar); im(B_bar)] bf16 [512][512]; Cbf bf16 [512][256]
// ---------------------------------------------------------------------------
__global__ __launch_bounds__(256) void prep_kernel(
    const float* __restrict__ A_real, const float* __restrict__ A_imag,
    const float* __restrict__ B_mat, const float* __restrict__ C_mat,
    float* __restrict__ abr, float* __restrict__ abi,
    unsigned short* __restrict__ bmbf, unsigned short* __restrict__ cbf) {
  const int n = blockIdx.x;
  const float ar = -fabsf(A_real[n]) - 5e-4f;
  const float ai = A_imag[n];
  const float dr = 1.0f - 0.005f * ar;
  const float di = -0.005f * ai;
  const float inv = 1.0f / (dr * dr + di * di);
  if (threadIdx.x == 0) {
    const float nr = 1.0f + 0.005f * ar;
    const float ni = 0.005f * ai;
    abr[n] = (nr * dr + ni * di) * inv;
    abi[n] = (ni * dr - nr * di) * inv;
  }
  const float cr = 0.01f * dr * inv;
  const float ci = -0.01f * di * inv;
  for (int d = threadIdx.x; d < DIN; d += blockDim.x) {
    const float bv = B_mat[n * DIN + d];
    bmbf[n * DIN + d]         = f2bf(bv * cr);
    bmbf[(NST + n) * DIN + d] = f2bf(bv * ci);
  }
  // convert C rows 2n, 2n+1 to bf16 (coalesced)
  const size_t cbase = (size_t)(2 * n) * NST;
  for (int i = threadIdx.x; i < 2 * NST; i += blockDim.x)
    cbf[cbase + i] = f2bf(C_mat[cbase + i]);
}

// ---------------------------------------------------------------------------
// cvt: U fp32 -> Ubf bf16 (8 elems/thread)
// ---------------------------------------------------------------------------
__global__ __launch_bounds__(256) void cvt_kernel(
    const float* __restrict__ U, unsigned short* __restrict__ Ubf) {
  const int i = blockIdx.x * 256 + threadIdx.x;   // chunk of 8
  const float4 f0 = reinterpret_cast<const float4*>(U)[i * 2];
  const float4 f1 = reinterpret_cast<const float4*>(U)[i * 2 + 1];
  unsigned short o[8] = {f2bf(f0.x), f2bf(f0.y), f2bf(f0.z), f2bf(f0.w),
                         f2bf(f1.x), f2bf(f1.y), f2bf(f1.z), f2bf(f1.w)};
  *reinterpret_cast<short8*>(&Ubf[(size_t)i * 8]) = *reinterpret_cast<short8*>(o);
}

// ---------------------------------------------------------------------------
// GEMM1 (MFMA): V[b][j][l] (bf16) = sum_d Ubf[m=(b,l)][d] * Bmbf[j][d]
// ---------------------------------------------------------------------------
__global__ __launch_bounds__(256, 2) void gemm1_mfma(
    const unsigned short* __restrict__ Ubf,
    const unsigned short* __restrict__ Bmbf,
    unsigned short* __restrict__ V) {
  __shared__ short At[2][128 * 32];
  __shared__ short Bt[2][128 * 32];
  const int tid  = threadIdx.x;
  const int wave = tid >> 6;
  const int lane = tid & 63;
  const int m0 = blockIdx.x * 128;
  const int j0 = blockIdx.y * 128;

  f32x4 acc[4][4];
#pragma unroll
  for (int i = 0; i < 4; ++i)
#pragma unroll
    for (int j = 0; j < 4; ++j) acc[i][j] = (f32x4)0.f;

  const int wr = wave >> 1, wc = wave & 1;
  const int cl = lane & 15;
  const int kq = lane >> 4;

#define STAGE(buf, k0)                                                          \
  {                                                                             \
    _Pragma("unroll")                                                           \
    for (int q = 0; q < 2; ++q) {                                               \
      const int row = wave * 32 + q * 16 + (lane >> 2);                         \
      const int kb  = lane & 3;                                                 \
      const unsigned short* gA = Ubf  + (size_t)(m0 + row) * 512 + (k0) + kb*8; \
      const unsigned short* gB = Bmbf + (size_t)(j0 + row) * 512 + (k0) + kb*8; \
      short* lA = &At[buf][(wave * 32 + q * 16) * 32];                          \
      short* lB = &Bt[buf][(wave * 32 + q * 16) * 32];                          \
      __builtin_amdgcn_global_load_lds(                                         \
          (const __attribute__((address_space(1))) void*)gA,                    \
          (__attribute__((address_space(3))) void*)lA, 16, 0, 0);               \
      __builtin_amdgcn_global_load_lds(                                         \
          (const __attribute__((address_space(1))) void*)gB,                    \
          (__attribute__((address_space(3))) void*)lB, 16, 0, 0);               \
    }                                                                           \
  }

  STAGE(0, 0)
  for (int s = 0; s < 16; ++s) {
    const int cur = s & 1;
    if (s < 15) STAGE(cur ^ 1, (s + 1) * 32)
    __syncthreads();
    short8 a[4], b[4];
#pragma unroll
    for (int f = 0; f < 4; ++f) {
      a[f] = *reinterpret_cast<const short8*>(&At[cur][(wr * 64 + f * 16 + cl) * 32 + kq * 8]);
      b[f] = *reinterpret_cast<const short8*>(&Bt[cur][(wc * 64 + f * 16 + cl) * 32 + kq * 8]);
    }
#pragma unroll
    for (int fm = 0; fm < 4; ++fm)
#pragma unroll
      for (int fn = 0; fn < 4; ++fn)
        acc[fm][fn] = __builtin_amdgcn_mfma_f32_16x16x32_bf16(a[fm], b[fn], acc[fm][fn], 0, 0, 0);
    __syncthreads();
  }
#undef STAGE

  const int bb    = m0 >> 12;
  const int lbase = (m0 & 4095);
#pragma unroll
  for (int fm = 0; fm < 4; ++fm)
#pragma unroll
    for (int fn = 0; fn < 4; ++fn) {
      const int jj = j0 + wc * 64 + fn * 16 + cl;
      const int ll = lbase + wr * 64 + fm * 16 + kq * 4;
      const f32x4 v = acc[fm][fn];
      unsigned short o[4] = {f2bf(v.x), f2bf(v.y), f2bf(v.z), f2bf(v.w)};
      *reinterpret_cast<ushort4*>(&V[((size_t)bb * 512 + jj) * L_SEQ + ll]) =
          *reinterpret_cast<ushort4*>(o);
    }
}

// ---------------------------------------------------------------------------
// scan: per (b,n), y[l] = A_bar*y[l-1] + v[l]; V bf16 in, Re(y) bf16 out
// ---------------------------------------------------------------------------
__global__ __launch_bounds__(256) void scan_kernel(
    const unsigned short* __restrict__ V, const float* __restrict__ abr,
    const float* __restrict__ abi, unsigned short* __restrict__ Y) {
  const int b = blockIdx.x >> 8;
  const int n = blockIdx.x & 255;
  const float ar = abr[n], ai = abi[n];
  const unsigned short* vre = V + ((size_t)b * 512 + n) * L_SEQ;
  const unsigned short* vim = V + ((size_t)b * 512 + NST + n) * L_SEQ;
  const int t = threadIdx.x;

  float xr[16], xi[16];
#pragma unroll
  for (int q = 0; q < 2; ++q) {
    const short8 r8 = *reinterpret_cast<const short8*>(&vre[t * 16 + q * 8]);
    const short8 i8 = *reinterpret_cast<const short8*>(&vim[t * 16 + q * 8]);
#pragma unroll
    for (int j = 0; j < 8; ++j) {
      xr[q * 8 + j] = bf2f((unsigned short)r8[j]);
      xi[q * 8 + j] = bf2f((unsigned short)i8[j]);
    }
  }
  float yr = 0.f, yi = 0.f;
#pragma unroll
  for (int i = 0; i < 16; ++i) {
    const float t1 = ar * yr - ai * yi + xr[i];
    yi = ar * yi + ai * yr + xi[i];
    yr = t1;
    xr[i] = yr; xi[i] = yi;
  }
  float fr = ar, fi = ai;
#pragma unroll
  for (int s = 0; s < 4; ++s) { const float t2 = fr * fr - fi * fi; fi = 2.f * fr * fi; fr = t2; }
  __shared__ float sr[256], si[256];
  float er = yr, ei = yi;
  for (int s = 1; s < 256; s <<= 1) {
    sr[t] = er; si[t] = ei;
    __syncthreads();
    if (t >= s) {
      const float pr = sr[t - s], pi = si[t - s];
      er += fr * pr - fi * pi;
      ei += fr * pi + fi * pr;
    }
    __syncthreads();
    const float t2 = fr * fr - fi * fi; fi = 2.f * fr * fi; fr = t2;
  }
  sr[t] = er; si[t] = ei;
  __syncthreads();
  float cr = 0.f, ci = 0.f;
  if (t > 0) { cr = sr[t - 1]; ci = si[t - 1]; }
  unsigned short o16[16];
  float gr = cr, gi = ci;
#pragma unroll
  for (int i = 0; i < 16; ++i) {
    const float t1 = ar * gr - ai * gi;
    gi = ar * gi + ai * gr;
    gr = t1;
    o16[i] = f2bf(xr[i] + gr);
  }
  unsigned short* yo = Y + ((size_t)b * NST + n) * L_SEQ + t * 16;
  *reinterpret_cast<short8*>(&yo[0]) = *reinterpret_cast<short8*>(&o16[0]);
  *reinterpret_cast<short8*>(&yo[8]) = *reinterpret_cast<short8*>(&o16[8]);
}

// ---------------------------------------------------------------------------
// transpose: Y[b][n][l] -> Yt[b][l][n]  (bf16, 64n x 256l tiles, swizzled LDS)
// ---------------------------------------------------------------------------
__global__ __launch_bounds__(256) void transp_kernel(
    const unsigned short* __restrict__ Y, unsigned short* __restrict__ Yt) {
  __shared__ unsigned short T[64 * 256];
  const int b  = blockIdx.z;
  const int n0 = blockIdx.y * 64;
  const int l0 = blockIdx.x * 256;
  const int t  = threadIdx.x;
  {
    const int nr = t >> 2;        // 0..63
    const int c4 = t & 3;
    const unsigned short* src = Y + ((size_t)b * NST + n0 + nr) * L_SEQ + l0;
#pragma unroll
    for (int h = 0; h < 8; ++h) {
      const int ch = c4 + h * 4;  // 0..31 (16B chunks of the 256-l row)
      const short8 v = *reinterpret_cast<const short8*>(&src[ch * 8]);
      const int p = ch ^ (nr & 7) ^ ((nr >> 3) & 3);   // bank swizzle
      *reinterpret_cast<short8*>(&T[nr * 256 + p * 8]) = v;
    }
  }
  __syncthreads();
  {
    const int c = t & 7;          // n-chunk 0..7
#pragma unroll
    for (int h2 = 0; h2 < 8; ++h2) {
      const int l = h2 * 32 + (t >> 3);   // 0..255
      unsigned short o[8];
#pragma unroll
      for (int j = 0; j < 8; ++j) {
        const int p = (l >> 3) ^ j ^ (c & 3);
        o[j] = T[(c * 8 + j) * 256 + p * 8 + (l & 7)];
      }
      *reinterpret_cast<short8*>(&Yt[((size_t)b * L_SEQ + l0 + l) * NST + n0 + c * 8]) =
          *reinterpret_cast<short8*>(o);
    }
  }
}

// ---------------------------------------------------------------------------
// GEMM2 (MFMA): out[(b,l)][d] = sum_n Cbf[d][n] * Yt[(b,l)][n] + U*Dv
// A = Cbf (M=d), B = Yt (N=(b,l)), K = n = 256
// ---------------------------------------------------------------------------
__global__ __launch_bounds__(256, 2) void gemm2_mfma(
    const unsigned short* __restrict__ Cbf,
    const unsigned short* __restrict__ Yt,
    const float* __restrict__ U,
    const float* __restrict__ Dv,
    float* __restrict__ out) {
  __shared__ short At[2][128 * 32];
  __shared__ short Bt[2][128 * 32];
  const int tid  = threadIdx.x;
  const int wave = tid >> 6;
  const int lane = tid & 63;
  const int m0 = blockIdx.x * 128;   // (b,l) rows
  const int d0 = blockIdx.y * 128;   // d rows

  f32x4 acc[4][4];
#pragma unroll
  for (int i = 0; i < 4; ++i)
#pragma unroll
    for (int j = 0; j < 4; ++j) acc[i][j] = (f32x4)0.f;

  const int wr = wave >> 1, wc = wave & 1;   // wr: d-quadrant, wc: l-quadrant
  const int cl = lane & 15;
  const int kq = lane >> 4;

#define STAGE2(buf, k0)                                                         \
  {                                                                             \
    _Pragma("unroll")                                                           \
    for (int q = 0; q < 2; ++q) {                                               \
      const int row = wave * 32 + q * 16 + (lane >> 2);                         \
      const int kb  = lane & 3;                                                 \
      const unsigned short* gA = Cbf + (size_t)(d0 + row) * 256 + (k0) + kb*8;  \
      const unsigned short* gB = Yt  + (size_t)(m0 + row) * 256 + (k0) + kb*8;  \
      short* lA = &At[buf][(wave * 32 + q * 16) * 32];                          \
      short* lB = &Bt[buf][(wave * 32 + q * 16) * 32];                          \
      __builtin_amdgcn_global_load_lds(                                         \
          (const __attribute__((address_space(1))) void*)gA,                    \
          (__attribute__((address_space(3))) void*)lA, 16, 0, 0);               \
      __builtin_amdgcn_global_load_lds(                                         \
          (const __attribute__((address_space(1))) void*)gB,                    \
          (__attribute__((address_space(3))) void*)lB, 16, 0, 0);               \
    }                                                                           \
  }

  STAGE2(0, 0)
  for (int s = 0; s < 8; ++s) {
    const int cur = s & 1;
    if (s < 7) STAGE2(cur ^ 1, (s + 1) * 32)
    __syncthreads();
    short8 a[4], b[4];
#pragma unroll
    for (int f = 0; f < 4; ++f) {
      a[f] = *reinterpret_cast<const short8*>(&At[cur][(wr * 64 + f * 16 + cl) * 32 + kq * 8]);
      b[f] = *reinterpret_cast<const short8*>(&Bt[cur][(wc * 64 + f * 16 + cl) * 32 + kq * 8]);
    }
#pragma unroll
    for (int fm = 0; fm < 4; ++fm)
#pragma unroll
      for (int fn = 0; fn < 4; ++fn)
        acc[fm][fn] = __builtin_amdgcn_mfma_f32_16x16x32_bf16(a[fm], b[fn], acc[fm][fn], 0, 0, 0);
    __syncthreads();
  }
#undef STAGE2

  // D[m=d][n'=l]: col l = cl, rows d = kq*4 + reg -> f32x4 store along d
#pragma unroll
  for (int fm = 0; fm < 4; ++fm) {
    const int dd = d0 + wr * 64 + fm * 16 + kq * 4;
    const f32x4 dvv = *reinterpret_cast<const f32x4*>(&Dv[dd]);
#pragma unroll
    for (int fn = 0; fn < 4; ++fn) {
      const size_t ll = m0 + wc * 64 + fn * 16 + cl;
      const size_t base = ll * 512 + dd;
      const f32x4 uv = *reinterpret_cast<const f32x4*>(&U[base]);
      f32x4 o = acc[fm][fn];
      o.x += uv.x * dvv.x; o.y += uv.y * dvv.y;
      o.z += uv.z * dvv.z; o.w += uv.w * dvv.w;
      *reinterpret_cast<f32x4*>(&out[base]) = o;
    }
  }
}

// ---------------------------------------------------------------------------
extern "C" void kernel_launch(void* const* d_in, const int* in_sizes, int n_in,
                              void* d_out, int out_size, void* d_ws, size_t ws_size,
                              hipStream_t stream) {
  const float* u      = (const float*)d_in[0];
  const float* A_real = (const float*)d_in[1];
  const float* A_imag = (const float*)d_in[2];
  const float* B_mat  = (const float*)d_in[3];
  const float* C_mat  = (const float*)d_in[4];
  const float* D_vec  = (const float*)d_in[5];
  float* out = (float*)d_out;

  unsigned short* bmbf = (unsigned short*)d_ws;            // 512*512
  unsigned short* cbf  = bmbf + 512 * 512;                 // 512*256
  float* abr = (float*)(cbf + 512 * 256);                  // 256
  float* abi = abr + 256;                                  // 256
  unsigned short* Ubf = (unsigned short*)(abi + 256);      // 16384*512
  unsigned short* V   = Ubf + (size_t)16384 * 512;         // 4*512*4096
  unsigned short* Y   = V + (size_t)4 * 512 * 4096;        // 4*256*4096
  unsigned short* Yt  = Y + (size_t)4 * 256 * 4096;        // 4*4096*256

  hipLaunchKernelGGL(prep_kernel, dim3(NST), dim3(256), 0, stream,
                     A_real, A_imag, B_mat, C_mat, abr, abi, bmbf, cbf);
  hipLaunchKernelGGL(cvt_kernel, dim3(4096), dim3(256), 0, stream, u, Ubf);
  hipLaunchKernelGGL(gemm1_mfma, dim3(128, 4), dim3(256), 0, stream, Ubf, bmbf, V);
  hipLaunchKernelGGL(scan_kernel, dim3(1024), dim3(256), 0, stream, V, abr, abi, Y);
  hipLaunchKernelGGL(transp_kernel, dim3(16, 4, 4), dim3(256), 0, stream, Y, Yt);
  hipLaunchKernelGGL(gemm2_mfma, dim3(128, 4), dim3(256), 0, stream, cbf, Yt, u, D_vec, out);
}

// Round 8
// 64.566 us; speedup vs baseline: 3.0634x; 1.0318x over previous
//
#include <hip/hip_runtime.h>

#define L_SEQ 4096
#define DIN   512
#define NST   256

typedef __attribute__((ext_vector_type(8))) short short8;
typedef __attribute__((ext_vector_type(4))) float f32x4;

__device__ inline unsigned short f2bf(float f) {
  unsigned u = __builtin_bit_cast(unsigned, f);
  unsigned r = (u + 0x7FFFu + ((u >> 16) & 1u)) >> 16;   // RTN-even
  return (unsigned short)r;
}
__device__ inline float bf2f(unsigned short h) {
  unsigned u = ((unsigned)h) << 16;
  return __builtin_bit_cast(float, u);
}

// ---------------------------------------------------------------------------
// prep: A_bar; Bmbf = [re(B_bar); im(B_bar)] bf16 [512][512]; Cbf bf16 [512][256]
// ---------------------------------------------------------------------------
__global__ __launch_bounds__(256) void prep_kernel(
    const float* __restrict__ A_real, const float* __restrict__ A_imag,
    const float* __restrict__ B_mat, const float* __restrict__ C_mat,
    float* __restrict__ abr, float* __restrict__ abi,
    unsigned short* __restrict__ bmbf, unsigned short* __restrict__ cbf) {
  const int n = blockIdx.x;
  const float ar = -fabsf(A_real[n]) - 5e-4f;
  const float ai = A_imag[n];
  const float dr = 1.0f - 0.005f * ar;
  const float di = -0.005f * ai;
  const float inv = 1.0f / (dr * dr + di * di);
  if (threadIdx.x == 0) {
    const float nr = 1.0f + 0.005f * ar;
    const float ni = 0.005f * ai;
    abr[n] = (nr * dr + ni * di) * inv;
    abi[n] = (ni * dr - nr * di) * inv;
  }
  const float cr = 0.01f * dr * inv;
  const float ci = -0.01f * di * inv;
  for (int d = threadIdx.x; d < DIN; d += blockDim.x) {
    const float bv = B_mat[n * DIN + d];
    bmbf[n * DIN + d]         = f2bf(bv * cr);
    bmbf[(NST + n) * DIN + d] = f2bf(bv * ci);
  }
  const size_t cbase = (size_t)(2 * n) * NST;
  for (int i = threadIdx.x; i < 2 * NST; i += blockDim.x)
    cbf[cbase + i] = f2bf(C_mat[cbase + i]);
}

// ---------------------------------------------------------------------------
// cvt: U fp32 -> Ubf bf16 (8 elems/thread)
// ---------------------------------------------------------------------------
__global__ __launch_bounds__(256) void cvt_kernel(
    const float* __restrict__ U, unsigned short* __restrict__ Ubf) {
  const int i = blockIdx.x * 256 + threadIdx.x;   // chunk of 8
  const float4 f0 = reinterpret_cast<const float4*>(U)[i * 2];
  const float4 f1 = reinterpret_cast<const float4*>(U)[i * 2 + 1];
  unsigned short o[8] = {f2bf(f0.x), f2bf(f0.y), f2bf(f0.z), f2bf(f0.w),
                         f2bf(f1.x), f2bf(f1.y), f2bf(f1.z), f2bf(f1.w)};
  *reinterpret_cast<short8*>(&Ubf[(size_t)i * 8]) = *reinterpret_cast<short8*>(o);
}

// ---------------------------------------------------------------------------
// GEMM1 (MFMA): V[b][j][l] (bf16) = sum_d Ubf[m=(b,l)][d] * Bmbf[j][d]
// ---------------------------------------------------------------------------
__global__ __launch_bounds__(256, 2) void gemm1_mfma(
    const unsigned short* __restrict__ Ubf,
    const unsigned short* __restrict__ Bmbf,
    unsigned short* __restrict__ V) {
  __shared__ short At[2][128 * 32];
  __shared__ short Bt[2][128 * 32];
  const int tid  = threadIdx.x;
  const int wave = tid >> 6;
  const int lane = tid & 63;
  const int m0 = blockIdx.x * 128;
  const int j0 = blockIdx.y * 128;

  f32x4 acc[4][4];
#pragma unroll
  for (int i = 0; i < 4; ++i)
#pragma unroll
    for (int j = 0; j < 4; ++j) acc[i][j] = (f32x4)0.f;

  const int wr = wave >> 1, wc = wave & 1;
  const int cl = lane & 15;
  const int kq = lane >> 4;

#define STAGE(buf, k0)                                                          \
  {                                                                             \
    _Pragma("unroll")                                                           \
    for (int q = 0; q < 2; ++q) {                                               \
      const int row = wave * 32 + q * 16 + (lane >> 2);                         \
      const int kb  = lane & 3;                                                 \
      const unsigned short* gA = Ubf  + (size_t)(m0 + row) * 512 + (k0) + kb*8; \
      const unsigned short* gB = Bmbf + (size_t)(j0 + row) * 512 + (k0) + kb*8; \
      short* lA = &At[buf][(wave * 32 + q * 16) * 32];                          \
      short* lB = &Bt[buf][(wave * 32 + q * 16) * 32];                          \
      __builtin_amdgcn_global_load_lds(                                         \
          (const __attribute__((address_space(1))) void*)gA,                    \
          (__attribute__((address_space(3))) void*)lA, 16, 0, 0);               \
      __builtin_amdgcn_global_load_lds(                                         \
          (const __attribute__((address_space(1))) void*)gB,                    \
          (__attribute__((address_space(3))) void*)lB, 16, 0, 0);               \
    }                                                                           \
  }

  STAGE(0, 0)
  for (int s = 0; s < 16; ++s) {
    const int cur = s & 1;
    if (s < 15) STAGE(cur ^ 1, (s + 1) * 32)
    __syncthreads();
    short8 a[4], b[4];
#pragma unroll
    for (int f = 0; f < 4; ++f) {
      a[f] = *reinterpret_cast<const short8*>(&At[cur][(wr * 64 + f * 16 + cl) * 32 + kq * 8]);
      b[f] = *reinterpret_cast<const short8*>(&Bt[cur][(wc * 64 + f * 16 + cl) * 32 + kq * 8]);
    }
#pragma unroll
    for (int fm = 0; fm < 4; ++fm)
#pragma unroll
      for (int fn = 0; fn < 4; ++fn)
        acc[fm][fn] = __builtin_amdgcn_mfma_f32_16x16x32_bf16(a[fm], b[fn], acc[fm][fn], 0, 0, 0);
    __syncthreads();
  }
#undef STAGE

  const int bb    = m0 >> 12;
  const int lbase = (m0 & 4095);
#pragma unroll
  for (int fm = 0; fm < 4; ++fm)
#pragma unroll
    for (int fn = 0; fn < 4; ++fn) {
      const int jj = j0 + wc * 64 + fn * 16 + cl;
      const int ll = lbase + wr * 64 + fm * 16 + kq * 4;
      const f32x4 v = acc[fm][fn];
      unsigned short o[4] = {f2bf(v.x), f2bf(v.y), f2bf(v.z), f2bf(v.w)};
      *reinterpret_cast<ushort4*>(&V[((size_t)bb * 512 + jj) * L_SEQ + ll]) =
          *reinterpret_cast<ushort4*>(o);
    }
}

// ---------------------------------------------------------------------------
// scan: per (b,n), y[l] = A_bar*y[l-1] + v[l]; V bf16 in, Re(y) bf16 out
// ---------------------------------------------------------------------------
__global__ __launch_bounds__(256) void scan_kernel(
    const unsigned short* __restrict__ V, const float* __restrict__ abr,
    const float* __restrict__ abi, unsigned short* __restrict__ Y) {
  const int b = blockIdx.x >> 8;
  const int n = blockIdx.x & 255;
  const float ar = abr[n], ai = abi[n];
  const unsigned short* vre = V + ((size_t)b * 512 + n) * L_SEQ;
  const unsigned short* vim = V + ((size_t)b * 512 + NST + n) * L_SEQ;
  const int t = threadIdx.x;

  float xr[16], xi[16];
#pragma unroll
  for (int q = 0; q < 2; ++q) {
    const short8 r8 = *reinterpret_cast<const short8*>(&vre[t * 16 + q * 8]);
    const short8 i8 = *reinterpret_cast<const short8*>(&vim[t * 16 + q * 8]);
#pragma unroll
    for (int j = 0; j < 8; ++j) {
      xr[q * 8 + j] = bf2f((unsigned short)r8[j]);
      xi[q * 8 + j] = bf2f((unsigned short)i8[j]);
    }
  }
  float yr = 0.f, yi = 0.f;
#pragma unroll
  for (int i = 0; i < 16; ++i) {
    const float t1 = ar * yr - ai * yi + xr[i];
    yi = ar * yi + ai * yr + xi[i];
    yr = t1;
    xr[i] = yr; xi[i] = yi;
  }
  float fr = ar, fi = ai;
#pragma unroll
  for (int s = 0; s < 4; ++s) { const float t2 = fr * fr - fi * fi; fi = 2.f * fr * fi; fr = t2; }
  __shared__ float sr[256], si[256];
  float er = yr, ei = yi;
  for (int s = 1; s < 256; s <<= 1) {
    sr[t] = er; si[t] = ei;
    __syncthreads();
    if (t >= s) {
      const float pr = sr[t - s], pi = si[t - s];
      er += fr * pr - fi * pi;
      ei += fr * pi + fi * pr;
    }
    __syncthreads();
    const float t2 = fr * fr - fi * fi; fi = 2.f * fr * fi; fr = t2;
  }
  sr[t] = er; si[t] = ei;
  __syncthreads();
  float cr = 0.f, ci = 0.f;
  if (t > 0) { cr = sr[t - 1]; ci = si[t - 1]; }
  unsigned short o16[16];
  float gr = cr, gi = ci;
#pragma unroll
  for (int i = 0; i < 16; ++i) {
    const float t1 = ar * gr - ai * gi;
    gi = ar * gi + ai * gr;
    gr = t1;
    o16[i] = f2bf(xr[i] + gr);
  }
  unsigned short* yo = Y + ((size_t)b * NST + n) * L_SEQ + t * 16;
  *reinterpret_cast<short8*>(&yo[0]) = *reinterpret_cast<short8*>(&o16[0]);
  *reinterpret_cast<short8*>(&yo[8]) = *reinterpret_cast<short8*>(&o16[8]);
}

// ---------------------------------------------------------------------------
// transpose: Y[b][n][l] -> Yt[b][l][n]  (bf16, 64n x 256l tiles, swizzled LDS)
// ---------------------------------------------------------------------------
__global__ __launch_bounds__(256) void transp_kernel(
    const unsigned short* __restrict__ Y, unsigned short* __restrict__ Yt) {
  __shared__ unsigned short T[64 * 256];
  const int b  = blockIdx.z;
  const int n0 = blockIdx.y * 64;
  const int l0 = blockIdx.x * 256;
  const int t  = threadIdx.x;
  {
    const int nr = t >> 2;        // 0..63
    const int c4 = t & 3;
    const unsigned short* src = Y + ((size_t)b * NST + n0 + nr) * L_SEQ + l0;
#pragma unroll
    for (int h = 0; h < 8; ++h) {
      const int ch = c4 + h * 4;  // 0..31 (16B chunks of the 256-l row)
      const short8 v = *reinterpret_cast<const short8*>(&src[ch * 8]);
      const int p = ch ^ (nr & 7) ^ ((nr >> 3) & 3);   // bank swizzle
      *reinterpret_cast<short8*>(&T[nr * 256 + p * 8]) = v;
    }
  }
  __syncthreads();
  {
    const int c = t & 7;          // n-chunk 0..7
#pragma unroll
    for (int h2 = 0; h2 < 8; ++h2) {
      const int l = h2 * 32 + (t >> 3);   // 0..255
      unsigned short o[8];
#pragma unroll
      for (int j = 0; j < 8; ++j) {
        const int p = (l >> 3) ^ j ^ (c & 3);
        o[j] = T[(c * 8 + j) * 256 + p * 8 + (l & 7)];
      }
      *reinterpret_cast<short8*>(&Yt[((size_t)b * L_SEQ + l0 + l) * NST + n0 + c * 8]) =
          *reinterpret_cast<short8*>(o);
    }
  }
}

// ---------------------------------------------------------------------------
// GEMM2 (MFMA): out[(b,l)][d] = sum_n Cbf[d][n] * Yt[(b,l)][n] + Ubf*Dv
// A = Cbf (M=d), B = Yt (N=(b,l)), K = n = 256.  Skip path reads bf16 Ubf.
// ---------------------------------------------------------------------------
__global__ __launch_bounds__(256, 2) void gemm2_mfma(
    const unsigned short* __restrict__ Cbf,
    const unsigned short* __restrict__ Yt,
    const unsigned short* __restrict__ Ubf,
    const float* __restrict__ Dv,
    float* __restrict__ out) {
  __shared__ short At[2][128 * 32];
  __shared__ short Bt[2][128 * 32];
  const int tid  = threadIdx.x;
  const int wave = tid >> 6;
  const int lane = tid & 63;
  const int m0 = blockIdx.x * 128;   // (b,l) rows
  const int d0 = blockIdx.y * 128;   // d rows

  f32x4 acc[4][4];
#pragma unroll
  for (int i = 0; i < 4; ++i)
#pragma unroll
    for (int j = 0; j < 4; ++j) acc[i][j] = (f32x4)0.f;

  const int wr = wave >> 1, wc = wave & 1;
  const int cl = lane & 15;
  const int kq = lane >> 4;

#define STAGE2(buf, k0)                                                         \
  {                                                                             \
    _Pragma("unroll")                                                           \
    for (int q = 0; q < 2; ++q) {                                               \
      const int row = wave * 32 + q * 16 + (lane >> 2);                         \
      const int kb  = lane & 3;                                                 \
      const unsigned short* gA = Cbf + (size_t)(d0 + row) * 256 + (k0) + kb*8;  \
      const unsigned short* gB = Yt  + (size_t)(m0 + row) * 256 + (k0) + kb*8;  \
      short* lA = &At[buf][(wave * 32 + q * 16) * 32];                          \
      short* lB = &Bt[buf][(wave * 32 + q * 16) * 32];                          \
      __builtin_amdgcn_global_load_lds(                                         \
          (const __attribute__((address_space(1))) void*)gA,                    \
          (__attribute__((address_space(3))) void*)lA, 16, 0, 0);               \
      __builtin_amdgcn_global_load_lds(                                         \
          (const __attribute__((address_space(1))) void*)gB,                    \
          (__attribute__((address_space(3))) void*)lB, 16, 0, 0);               \
    }                                                                           \
  }

  STAGE2(0, 0)
  for (int s = 0; s < 8; ++s) {
    const int cur = s & 1;
    if (s < 7) STAGE2(cur ^ 1, (s + 1) * 32)
    __syncthreads();
    short8 a[4], b[4];
#pragma unroll
    for (int f = 0; f < 4; ++f) {
      a[f] = *reinterpret_cast<const short8*>(&At[cur][(wr * 64 + f * 16 + cl) * 32 + kq * 8]);
      b[f] = *reinterpret_cast<const short8*>(&Bt[cur][(wc * 64 + f * 16 + cl) * 32 + kq * 8]);
    }
#pragma unroll
    for (int fm = 0; fm < 4; ++fm)
#pragma unroll
      for (int fn = 0; fn < 4; ++fn)
        acc[fm][fn] = __builtin_amdgcn_mfma_f32_16x16x32_bf16(a[fm], b[fn], acc[fm][fn], 0, 0, 0);
    __syncthreads();
  }
#undef STAGE2

  // D[m=d][n'=l]: col l = cl, rows d = kq*4 + reg -> f32x4 store along d
#pragma unroll
  for (int fm = 0; fm < 4; ++fm) {
    const int dd = d0 + wr * 64 + fm * 16 + kq * 4;
    const f32x4 dvv = *reinterpret_cast<const f32x4*>(&Dv[dd]);
#pragma unroll
    for (int fn = 0; fn < 4; ++fn) {
      const size_t ll = m0 + wc * 64 + fn * 16 + cl;
      const size_t base = ll * 512 + dd;
      const ushort4 ub = *reinterpret_cast<const ushort4*>(&Ubf[base]);
      f32x4 o = acc[fm][fn];
      o.x += bf2f(ub.x) * dvv.x; o.y += bf2f(ub.y) * dvv.y;
      o.z += bf2f(ub.z) * dvv.z; o.w += bf2f(ub.w) * dvv.w;
      *reinterpret_cast<f32x4*>(&out[base]) = o;
    }
  }
}

// ---------------------------------------------------------------------------
extern "C" void kernel_launch(void* const* d_in, const int* in_sizes, int n_in,
                              void* d_out, int out_size, void* d_ws, size_t ws_size,
                              hipStream_t stream) {
  const float* u      = (const float*)d_in[0];
  const float* A_real = (const float*)d_in[1];
  const float* A_imag = (const float*)d_in[2];
  const float* B_mat  = (const float*)d_in[3];
  const float* C_mat  = (const float*)d_in[4];
  const float* D_vec  = (const float*)d_in[5];
  float* out = (float*)d_out;

  unsigned short* bmbf = (unsigned short*)d_ws;            // 512*512
  unsigned short* cbf  = bmbf + 512 * 512;                 // 512*256
  float* abr = (float*)(cbf + 512 * 256);                  // 256
  float* abi = abr + 256;                                  // 256
  unsigned short* Ubf = (unsigned short*)(abi + 256);      // 16384*512
  unsigned short* V   = Ubf + (size_t)16384 * 512;         // 4*512*4096
  unsigned short* Y   = V + (size_t)4 * 512 * 4096;        // 4*256*4096
  unsigned short* Yt  = Y + (size_t)4 * 256 * 4096;        // 4*4096*256

  hipLaunchKernelGGL(prep_kernel, dim3(NST), dim3(256), 0, stream,
                     A_real, A_imag, B_mat, C_mat, abr, abi, bmbf, cbf);
  hipLaunchKernelGGL(cvt_kernel, dim3(4096), dim3(256), 0, stream, u, Ubf);
  hipLaunchKernelGGL(gemm1_mfma, dim3(128, 4), dim3(256), 0, stream, Ubf, bmbf, V);
  hipLaunchKernelGGL(scan_kernel, dim3(1024), dim3(256), 0, stream, V, abr, abi, Y);
  hipLaunchKernelGGL(transp_kernel, dim3(16, 4, 4), dim3(256), 0, stream, Y, Yt);
  hipLaunchKernelGGL(gemm2_mfma, dim3(128, 4), dim3(256), 0, stream, cbf, Yt, Ubf, D_vec, out);
}

// Round 9
// 58.880 us; speedup vs baseline: 3.3593x; 1.0966x over previous
//
#include <hip/hip_runtime.h>

#define L_SEQ 4096
#define DIN   512
#define NST   256

typedef __attribute__((ext_vector_type(8))) short short8;
typedef __attribute__((ext_vector_type(4))) float f32x4;

__device__ inline unsigned short f2bf(float f) {
  unsigned u = __builtin_bit_cast(unsigned, f);
  unsigned r = (u + 0x7FFFu + ((u >> 16) & 1u)) >> 16;   // RTN-even
  return (unsigned short)r;
}
__device__ inline float bf2f(unsigned short h) {
  unsigned u = ((unsigned)h) << 16;
  return __builtin_bit_cast(float, u);
}

// ---------------------------------------------------------------------------
// prep+cvt merged: all 4096 blocks convert U; blocks 0..255 also do prep for n
// ---------------------------------------------------------------------------
__global__ __launch_bounds__(256) void prepcvt_kernel(
    const float* __restrict__ U, const float* __restrict__ A_real,
    const float* __restrict__ A_imag, const float* __restrict__ B_mat,
    const float* __restrict__ C_mat, float* __restrict__ abr,
    float* __restrict__ abi, unsigned short* __restrict__ bmbf,
    unsigned short* __restrict__ cbf, unsigned short* __restrict__ Ubf) {
  const int i = blockIdx.x * 256 + threadIdx.x;   // chunk of 8
  const float4 f0 = reinterpret_cast<const float4*>(U)[i * 2];
  const float4 f1 = reinterpret_cast<const float4*>(U)[i * 2 + 1];
  unsigned short o[8] = {f2bf(f0.x), f2bf(f0.y), f2bf(f0.z), f2bf(f0.w),
                         f2bf(f1.x), f2bf(f1.y), f2bf(f1.z), f2bf(f1.w)};
  *reinterpret_cast<short8*>(&Ubf[(size_t)i * 8]) = *reinterpret_cast<short8*>(o);

  const int n = blockIdx.x;
  if (n < NST) {
    const float ar = -fabsf(A_real[n]) - 5e-4f;
    const float ai = A_imag[n];
    const float dr = 1.0f - 0.005f * ar;
    const float di = -0.005f * ai;
    const float inv = 1.0f / (dr * dr + di * di);
    if (threadIdx.x == 0) {
      const float nr = 1.0f + 0.005f * ar;
      const float ni = 0.005f * ai;
      abr[n] = (nr * dr + ni * di) * inv;
      abi[n] = (ni * dr - nr * di) * inv;
    }
    const float cr = 0.01f * dr * inv;
    const float ci = -0.01f * di * inv;
    for (int d = threadIdx.x; d < DIN; d += blockDim.x) {
      const float bv = B_mat[n * DIN + d];
      bmbf[n * DIN + d]         = f2bf(bv * cr);
      bmbf[(NST + n) * DIN + d] = f2bf(bv * ci);
    }
    const size_t cbase = (size_t)(2 * n) * NST;
    for (int k = threadIdx.x; k < 2 * NST; k += blockDim.x)
      cbf[cbase + k] = f2bf(C_mat[cbase + k]);
  }
}

// ---------------------------------------------------------------------------
// GEMM1 (MFMA): V[b][j][l] (bf16) = sum_d Ubf[m=(b,l)][d] * Bmbf[j][d]
// ---------------------------------------------------------------------------
__global__ __launch_bounds__(256, 2) void gemm1_mfma(
    const unsigned short* __restrict__ Ubf,
    const unsigned short* __restrict__ Bmbf,
    unsigned short* __restrict__ V) {
  __shared__ short At[2][128 * 32];
  __shared__ short Bt[2][128 * 32];
  const int tid  = threadIdx.x;
  const int wave = tid >> 6;
  const int lane = tid & 63;
  const int m0 = blockIdx.x * 128;
  const int j0 = blockIdx.y * 128;

  f32x4 acc[4][4];
#pragma unroll
  for (int i = 0; i < 4; ++i)
#pragma unroll
    for (int j = 0; j < 4; ++j) acc[i][j] = (f32x4)0.f;

  const int wr = wave >> 1, wc = wave & 1;
  const int cl = lane & 15;
  const int kq = lane >> 4;

#define STAGE(buf, k0)                                                          \
  {                                                                             \
    _Pragma("unroll")                                                           \
    for (int q = 0; q < 2; ++q) {                                               \
      const int row = wave * 32 + q * 16 + (lane >> 2);                         \
      const int kb  = lane & 3;                                                 \
      const unsigned short* gA = Ubf  + (size_t)(m0 + row) * 512 + (k0) + kb*8; \
      const unsigned short* gB = Bmbf + (size_t)(j0 + row) * 512 + (k0) + kb*8; \
      short* lA = &At[buf][(wave * 32 + q * 16) * 32];                          \
      short* lB = &Bt[buf][(wave * 32 + q * 16) * 32];                          \
      __builtin_amdgcn_global_load_lds(                                         \
          (const __attribute__((address_space(1))) void*)gA,                    \
          (__attribute__((address_space(3))) void*)lA, 16, 0, 0);               \
      __builtin_amdgcn_global_load_lds(                                         \
          (const __attribute__((address_space(1))) void*)gB,                    \
          (__attribute__((address_space(3))) void*)lB, 16, 0, 0);               \
    }                                                                           \
  }

  STAGE(0, 0)
  for (int s = 0; s < 16; ++s) {
    const int cur = s & 1;
    if (s < 15) STAGE(cur ^ 1, (s + 1) * 32)
    __syncthreads();
    short8 a[4], b[4];
#pragma unroll
    for (int f = 0; f < 4; ++f) {
      a[f] = *reinterpret_cast<const short8*>(&At[cur][(wr * 64 + f * 16 + cl) * 32 + kq * 8]);
      b[f] = *reinterpret_cast<const short8*>(&Bt[cur][(wc * 64 + f * 16 + cl) * 32 + kq * 8]);
    }
#pragma unroll
    for (int fm = 0; fm < 4; ++fm)
#pragma unroll
      for (int fn = 0; fn < 4; ++fn)
        acc[fm][fn] = __builtin_amdgcn_mfma_f32_16x16x32_bf16(a[fm], b[fn], acc[fm][fn], 0, 0, 0);
    __syncthreads();
  }
#undef STAGE

  const int bb    = m0 >> 12;
  const int lbase = (m0 & 4095);
#pragma unroll
  for (int fm = 0; fm < 4; ++fm)
#pragma unroll
    for (int fn = 0; fn < 4; ++fn) {
      const int jj = j0 + wc * 64 + fn * 16 + cl;
      const int ll = lbase + wr * 64 + fm * 16 + kq * 4;
      const f32x4 v = acc[fm][fn];
      unsigned short o[4] = {f2bf(v.x), f2bf(v.y), f2bf(v.z), f2bf(v.w)};
      *reinterpret_cast<ushort4*>(&V[((size_t)bb * 512 + jj) * L_SEQ + ll]) =
          *reinterpret_cast<ushort4*>(o);
    }
}

// ---------------------------------------------------------------------------
// scan: per (b,n), y[l] = A_bar*y[l-1] + v[l]; V bf16 in, Re(y) bf16 out
// wave-level shfl scan (factor a^16, squared per step) + single-barrier
// cross-wave carry (Horner with G=a^1024); exclusive state X per thread.
// ---------------------------------------------------------------------------
__global__ __launch_bounds__(256) void scan_kernel(
    const unsigned short* __restrict__ V, const float* __restrict__ abr,
    const float* __restrict__ abi, unsigned short* __restrict__ Y) {
  const int b = blockIdx.x >> 8;
  const int n = blockIdx.x & 255;
  const float ar = abr[n], ai = abi[n];
  const unsigned short* vre = V + ((size_t)b * 512 + n) * L_SEQ;
  const unsigned short* vim = V + ((size_t)b * 512 + NST + n) * L_SEQ;
  const int t = threadIdx.x;
  const int lane = t & 63;
  const int wid  = t >> 6;

  float xr[16], xi[16];
#pragma unroll
  for (int q = 0; q < 2; ++q) {
    const short8 r8 = *reinterpret_cast<const short8*>(&vre[t * 16 + q * 8]);
    const short8 i8 = *reinterpret_cast<const short8*>(&vim[t * 16 + q * 8]);
#pragma unroll
    for (int j = 0; j < 8; ++j) {
      xr[q * 8 + j] = bf2f((unsigned short)r8[j]);
      xi[q * 8 + j] = bf2f((unsigned short)i8[j]);
    }
  }
  // local sequential scan (16 elems)
  float yr = 0.f, yi = 0.f;
#pragma unroll
  for (int i = 0; i < 16; ++i) {
    const float t1 = ar * yr - ai * yi + xr[i];
    yi = ar * yi + ai * yr + xi[i];
    yr = t1;
    xr[i] = yr; xi[i] = yi;
  }
  // f = a^16
  float fr = ar, fi = ai;
#pragma unroll
  for (int s = 0; s < 4; ++s) { const float t2 = fr * fr - fi * fi; fi = 2.f * fr * fi; fr = t2; }

  // wave-level inclusive Hillis-Steele over 64 lanes; save F_k = f^(2^k)
  float er = yr, ei = yi;
  float Fr = fr, Fi = fi;
  float Fkr[6], Fki[6];
#pragma unroll
  for (int s = 0; s < 6; ++s) {
    Fkr[s] = Fr; Fki[s] = Fi;
    const float pr = __shfl_up(er, 1 << s);
    const float pi = __shfl_up(ei, 1 << s);
    if (lane >= (1 << s)) {
      er += Fr * pr - Fi * pi;
      ei += Fr * pi + Fi * pr;
    }
    const float t2 = Fr * Fr - Fi * Fi; Fi = 2.f * Fr * Fi; Fr = t2;
  }
  // Fr,Fi = f^64 = a^1024 = G

  // wave totals -> LDS, one barrier
  __shared__ float twr[4], twi[4];
  if (lane == 63) { twr[wid] = er; twi[wid] = ei; }
  __syncthreads();
  // C_w = sum_{w'<wid} G^{wid-1-w'} T_{w'}  (Horner)
  float cwr = 0.f, cwi = 0.f;
  for (int w = 0; w < wid; ++w) {
    const float t2 = Fr * cwr - Fi * cwi + twr[w];
    cwi = Fr * cwi + Fi * cwr + twi[w];
    cwr = t2;
  }
  // exclusive within wave: S_{lane-1}
  float sxr = __shfl_up(er, 1);
  float sxi = __shfl_up(ei, 1);
  if (lane == 0) { sxr = 0.f; sxi = 0.f; }
  // f^lane via binary powers
  float plr = 1.f, pli = 0.f;
#pragma unroll
  for (int s = 0; s < 6; ++s) {
    if (lane & (1 << s)) {
      const float t2 = plr * Fkr[s] - pli * Fki[s];
      pli = plr * Fki[s] + pli * Fkr[s];
      plr = t2;
    }
  }
  // X = S_excl + f^lane * C_w
  float cr = sxr + plr * cwr - pli * cwi;
  float ci = sxi + plr * cwi + pli * cwr;

  // fixup: y_global_i = y_local_i + a^(i+1) * X ; keep real part, bf16
  unsigned short o16[16];
  float gr = cr, gi = ci;
#pragma unroll
  for (int i = 0; i < 16; ++i) {
    const float t1 = ar * gr - ai * gi;
    gi = ar * gi + ai * gr;
    gr = t1;
    o16[i] = f2bf(xr[i] + gr);
  }
  unsigned short* yo = Y + ((size_t)b * NST + n) * L_SEQ + t * 16;
  *reinterpret_cast<short8*>(&yo[0]) = *reinterpret_cast<short8*>(&o16[0]);
  *reinterpret_cast<short8*>(&yo[8]) = *reinterpret_cast<short8*>(&o16[8]);
}

// ---------------------------------------------------------------------------
// transpose: Y[b][n][l] -> Yt[b][l][n]  (bf16, 64n x 256l tiles, swizzled LDS)
// ---------------------------------------------------------------------------
__global__ __launch_bounds__(256) void transp_kernel(
    const unsigned short* __restrict__ Y, unsigned short* __restrict__ Yt) {
  __shared__ unsigned short T[64 * 256];
  const int b  = blockIdx.z;
  const int n0 = blockIdx.y * 64;
  const int l0 = blockIdx.x * 256;
  const int t  = threadIdx.x;
  {
    const int nr = t >> 2;        // 0..63
    const int c4 = t & 3;
    const unsigned short* src = Y + ((size_t)b * NST + n0 + nr) * L_SEQ + l0;
#pragma unroll
    for (int h = 0; h < 8; ++h) {
      const int ch = c4 + h * 4;  // 0..31 (16B chunks of the 256-l row)
      const short8 v = *reinterpret_cast<const short8*>(&src[ch * 8]);
      const int p = ch ^ (nr & 7) ^ ((nr >> 3) & 3);   // bank swizzle
      *reinterpret_cast<short8*>(&T[nr * 256 + p * 8]) = v;
    }
  }
  __syncthreads();
  {
    const int c = t & 7;          // n-chunk 0..7
#pragma unroll
    for (int h2 = 0; h2 < 8; ++h2) {
      const int l = h2 * 32 + (t >> 3);   // 0..255
      unsigned short o[8];
#pragma unroll
      for (int j = 0; j < 8; ++j) {
        const int p = (l >> 3) ^ j ^ (c & 3);
        o[j] = T[(c * 8 + j) * 256 + p * 8 + (l & 7)];
      }
      *reinterpret_cast<short8*>(&Yt[((size_t)b * L_SEQ + l0 + l) * NST + n0 + c * 8]) =
          *reinterpret_cast<short8*>(o);
    }
  }
}

// ---------------------------------------------------------------------------
// GEMM2 (MFMA): out[(b,l)][d] = sum_n Cbf[d][n] * Yt[(b,l)][n] + Ubf*Dv
// ---------------------------------------------------------------------------
__global__ __launch_bounds__(256, 2) void gemm2_mfma(
    const unsigned short* __restrict__ Cbf,
    const unsigned short* __restrict__ Yt,
    const unsigned short* __restrict__ Ubf,
    const float* __restrict__ Dv,
    float* __restrict__ out) {
  __shared__ short At[2][128 * 32];
  __shared__ short Bt[2][128 * 32];
  const int tid  = threadIdx.x;
  const int wave = tid >> 6;
  const int lane = tid & 63;
  const int m0 = blockIdx.x * 128;   // (b,l) rows
  const int d0 = blockIdx.y * 128;   // d rows

  f32x4 acc[4][4];
#pragma unroll
  for (int i = 0; i < 4; ++i)
#pragma unroll
    for (int j = 0; j < 4; ++j) acc[i][j] = (f32x4)0.f;

  const int wr = wave >> 1, wc = wave & 1;
  const int cl = lane & 15;
  const int kq = lane >> 4;

#define STAGE2(buf, k0)                                                         \
  {                                                                             \
    _Pragma("unroll")                                                           \
    for (int q = 0; q < 2; ++q) {                                               \
      const int row = wave * 32 + q * 16 + (lane >> 2);                         \
      const int kb  = lane & 3;                                                 \
      const unsigned short* gA = Cbf + (size_t)(d0 + row) * 256 + (k0) + kb*8;  \
      const unsigned short* gB = Yt  + (size_t)(m0 + row) * 256 + (k0) + kb*8;  \
      short* lA = &At[buf][(wave * 32 + q * 16) * 32];                          \
      short* lB = &Bt[buf][(wave * 32 + q * 16) * 32];                          \
      __builtin_amdgcn_global_load_lds(                                         \
          (const __attribute__((address_space(1))) void*)gA,                    \
          (__attribute__((address_space(3))) void*)lA, 16, 0, 0);               \
      __builtin_amdgcn_global_load_lds(                                         \
          (const __attribute__((address_space(1))) void*)gB,                    \
          (__attribute__((address_space(3))) void*)lB, 16, 0, 0);               \
    }                                                                           \
  }

  STAGE2(0, 0)
  for (int s = 0; s < 8; ++s) {
    const int cur = s & 1;
    if (s < 7) STAGE2(cur ^ 1, (s + 1) * 32)
    __syncthreads();
    short8 a[4], b[4];
#pragma unroll
    for (int f = 0; f < 4; ++f) {
      a[f] = *reinterpret_cast<const short8*>(&At[cur][(wr * 64 + f * 16 + cl) * 32 + kq * 8]);
      b[f] = *reinterpret_cast<const short8*>(&Bt[cur][(wc * 64 + f * 16 + cl) * 32 + kq * 8]);
    }
#pragma unroll
    for (int fm = 0; fm < 4; ++fm)
#pragma unroll
      for (int fn = 0; fn < 4; ++fn)
        acc[fm][fn] = __builtin_amdgcn_mfma_f32_16x16x32_bf16(a[fm], b[fn], acc[fm][fn], 0, 0, 0);
    __syncthreads();
  }
#undef STAGE2

#pragma unroll
  for (int fm = 0; fm < 4; ++fm) {
    const int dd = d0 + wr * 64 + fm * 16 + kq * 4;
    const f32x4 dvv = *reinterpret_cast<const f32x4*>(&Dv[dd]);
#pragma unroll
    for (int fn = 0; fn < 4; ++fn) {
      const size_t ll = m0 + wc * 64 + fn * 16 + cl;
      const size_t base = ll * 512 + dd;
      const ushort4 ub = *reinterpret_cast<const ushort4*>(&Ubf[base]);
      f32x4 o = acc[fm][fn];
      o.x += bf2f(ub.x) * dvv.x; o.y += bf2f(ub.y) * dvv.y;
      o.z += bf2f(ub.z) * dvv.z; o.w += bf2f(ub.w) * dvv.w;
      *reinterpret_cast<f32x4*>(&out[base]) = o;
    }
  }
}

// ---------------------------------------------------------------------------
extern "C" void kernel_launch(void* const* d_in, const int* in_sizes, int n_in,
                              void* d_out, int out_size, void* d_ws, size_t ws_size,
                              hipStream_t stream) {
  const float* u      = (const float*)d_in[0];
  const float* A_real = (const float*)d_in[1];
  const float* A_imag = (const float*)d_in[2];
  const float* B_mat  = (const float*)d_in[3];
  const float* C_mat  = (const float*)d_in[4];
  const float* D_vec  = (const float*)d_in[5];
  float* out = (float*)d_out;

  unsigned short* bmbf = (unsigned short*)d_ws;            // 512*512
  unsigned short* cbf  = bmbf + 512 * 512;                 // 512*256
  float* abr = (float*)(cbf + 512 * 256);                  // 256
  float* abi = abr + 256;                                  // 256
  unsigned short* Ubf = (unsigned short*)(abi + 256);      // 16384*512
  unsigned short* V   = Ubf + (size_t)16384 * 512;         // 4*512*4096
  unsigned short* Y   = V + (size_t)4 * 512 * 4096;        // 4*256*4096
  unsigned short* Yt  = Y + (size_t)4 * 256 * 4096;        // 4*4096*256

  hipLaunchKernelGGL(prepcvt_kernel, dim3(4096), dim3(256), 0, stream,
                     u, A_real, A_imag, B_mat, C_mat, abr, abi, bmbf, cbf, Ubf);
  hipLaunchKernelGGL(gemm1_mfma, dim3(128, 4), dim3(256), 0, stream, Ubf, bmbf, V);
  hipLaunchKernelGGL(scan_kernel, dim3(1024), dim3(256), 0, stream, V, abr, abi, Y);
  hipLaunchKernelGGL(transp_kernel, dim3(16, 4, 4), dim3(256), 0, stream, Y, Yt);
  hipLaunchKernelGGL(gemm2_mfma, dim3(128, 4), dim3(256), 0, stream, cbf, Yt, Ubf, D_vec, out);
}